// Round 8
// baseline (291.986 us; speedup 1.0000x reference)
//
#include <hip/hip_runtime.h>
#include <math.h>

typedef short bf16x8 __attribute__((ext_vector_type(8)));
typedef float f32x4 __attribute__((ext_vector_type(4)));
typedef float fvec4 __attribute__((ext_vector_type(4)));   // for nontemporal vector loads

#define EBK 128   // edges per block (edge path)
#define NBK 64    // rows per block (node path)

__device__ __forceinline__ float silu_f(float x) {
  return x / (1.0f + __expf(-x));
}
__device__ __forceinline__ unsigned short f2bf(float x) {
  union { float f; unsigned u; } v; v.f = x;
  unsigned r = v.u + 0x7FFFu + ((v.u >> 16) & 1u);   // round-nearest-even
  return (unsigned short)(r >> 16);
}
__device__ __forceinline__ float bf2f(unsigned short h) {
  union { unsigned u; float f; } v; v.u = ((unsigned)h) << 16; return v.f;
}

// ---- prep: build bf16 transposed weights in ws ----
// wet:  [64 cols][96 K]   at ws[0..6144)        (K 85..95 zero)
// w1t:  [128 cols][160 K] at ws[6144..26624)
// w2t:  [128 cols][128 K] at ws[26624..43008)
__global__ __launch_bounds__(256)
void prep_kernel(const float* __restrict__ W1, const float* __restrict__ W2,
                 const float* __restrict__ We, unsigned short* __restrict__ ws)
{
  int i = blockIdx.x * 256 + threadIdx.x;
  if (i < 6144) {
    int col = i / 96, k = i - col * 96;
    float v = (k < 85) ? We[k * 64 + col] : 0.0f;
    ws[i] = f2bf(v);
  }
  int j = i - 6144;
  if (j >= 0 && j < 20480) {
    int col = j / 160, k = j - col * 160;
    ws[6144 + j] = f2bf(W1[k * 128 + col]);
  }
  int l = i - 26624;
  if (l >= 0 && l < 16384) {
    int col = l >> 7, k = l & 127;
    ws[26624 + l] = f2bf(W2[k * 128 + col]);
  }
}

struct EdgeSmem { unsigned short A[EBK][104]; };                      // 26.6 KB
struct NodeSmem { unsigned short A1[NBK][168]; unsigned short H[NBK][136]; }; // 38.9 KB
union FusedSmem { EdgeSmem e; NodeSmem n; };

// ================= fused kernel: edge blocks + node blocks =================
// bid%5==4 -> node block (node:edge block ratio is 1563:6250 ~= 1:4).
__global__ __launch_bounds__(256, 4)
void fused_kernel(const float* __restrict__ s_t,
                  const float* __restrict__ x_t,
                  const float* __restrict__ v_t,
                  const float* __restrict__ e_t,
                  const float* __restrict__ dst_lig_x,
                  const float* __restrict__ dst_lig_a,
                  const float* __restrict__ dst_lig_e,
                  const int* __restrict__ edge_src,
                  const int* __restrict__ edge_dst,
                  const unsigned short* __restrict__ wsw,
                  const float* __restrict__ b1, const float* __restrict__ b2,
                  const float* __restrict__ be,
                  float* __restrict__ node_out, float* __restrict__ v_out,
                  float* __restrict__ e_out0, float* __restrict__ e_out1,
                  int N, int Eu, int nNodeBlk, int nEdgeBlk)
{
  __shared__ FusedSmem sm;
  const int bid = blockIdx.x;
  const int t = threadIdx.x;
  const int w = t >> 6, lane = t & 63;

  if (bid % 5 == 4) {
    // ---------------- node path ----------------
    const int nb = bid / 5;
    if (nb >= nNodeBlk) return;
    const int row0 = nb * NBK;
    const unsigned short* w1t = wsw + 6144;
    const unsigned short* w2t = wsw + 26624;
    auto& A1 = sm.n.A1;
    auto& H  = sm.n.H;

    // stage s_t -> A1 cols 32..159
    #pragma unroll
    for (int p = 0; p < 8; ++p) {
      int i = p * 256 + t;
      int row = i >> 5, q = i & 31;
      if (row0 + row < N) {
        const fvec4 v = __builtin_nontemporal_load(
            reinterpret_cast<const fvec4*>(&s_t[(size_t)(row0 + row) * 128 + q * 4]));
        uint2 pk;
        pk.x = f2bf(v.x) | ((unsigned)f2bf(v.y) << 16);
        pk.y = f2bf(v.z) | ((unsigned)f2bf(v.w) << 16);
        *reinterpret_cast<uint2*>(&A1[row][32 + q * 4]) = pk;
      }
    }
    // rbf + dst_lig_a -> A1 cols 0..31; v_out (broadcast distance recompute)
    #pragma unroll
    for (int p = 0; p < 4; ++p) {
      int i = p * 256 + t;
      int el = i >> 4, m = i & 15;
      int row = row0 + el;
      if (row < N) {
        float dx = dst_lig_x[row*3+0] - x_t[row*3+0];
        float dy = dst_lig_x[row*3+1] - x_t[row*3+1];
        float dz = dst_lig_x[row*3+2] - x_t[row*3+2];
        float dij = sqrtf(fmaxf(dx*dx + dy*dy + dz*dz, 1e-8f));
        float tt = (dij - 0.66666667f * (float)m) * 1.6f;
        A1[el][m]      = f2bf(__expf(-tt * tt));
        A1[el][16 + m] = f2bf(dst_lig_a[(size_t)row * 16 + m]);
        if (m < 12) {
          float val;
          if (m < 9)       val = v_t[(size_t)row * 12 + m];
          else if (m == 9) val = dx / dij;
          else if (m == 10)val = dy / dij;
          else             val = dz / dij;
          __builtin_nontemporal_store(val, &v_out[(size_t)row * 12 + m]);
        }
      }
    }
    __syncthreads();

    const int mb = (w & 1) * 32;   // 2 m-tiles
    const int nb2 = (w >> 1) * 64; // 4 n-tiles

    // layer 1: K=160, 5 k-steps
    f32x4 acc[2][4] = {};
    #pragma unroll 1
    for (int ks = 0; ks < 5; ++ks) {
      const int ko = ks * 32 + ((lane >> 4) << 3);
      bf16x8 af[2], bfr[4];
      #pragma unroll
      for (int m = 0; m < 2; ++m)
        af[m] = *reinterpret_cast<const bf16x8*>(&A1[mb + m*16 + (lane & 15)][ko]);
      #pragma unroll
      for (int n = 0; n < 4; ++n)
        bfr[n] = *reinterpret_cast<const bf16x8*>(&w1t[(size_t)(nb2 + n*16 + (lane & 15)) * 160 + ko]);
      #pragma unroll
      for (int m = 0; m < 2; ++m)
        #pragma unroll
        for (int n = 0; n < 4; ++n)
          acc[m][n] = __builtin_amdgcn_mfma_f32_16x16x32_bf16(af[m], bfr[n], acc[m][n], 0, 0, 0);
    }
    #pragma unroll
    for (int n = 0; n < 4; ++n) {
      float bb = b1[nb2 + n*16 + (lane & 15)];
      #pragma unroll
      for (int m = 0; m < 2; ++m) {
        int r0 = mb + m*16 + ((lane >> 4) << 2);
        int c  = nb2 + n*16 + (lane & 15);
        #pragma unroll
        for (int r = 0; r < 4; ++r)
          H[r0 + r][c] = f2bf(silu_f(acc[m][n][r] + bb));
      }
    }
    __syncthreads();

    // layer 2: K=128, 4 k-steps
    f32x4 acc2[2][4] = {};
    #pragma unroll 1
    for (int ks = 0; ks < 4; ++ks) {
      const int ko = ks * 32 + ((lane >> 4) << 3);
      bf16x8 af[2], bfr[4];
      #pragma unroll
      for (int m = 0; m < 2; ++m)
        af[m] = *reinterpret_cast<const bf16x8*>(&H[mb + m*16 + (lane & 15)][ko]);
      #pragma unroll
      for (int n = 0; n < 4; ++n)
        bfr[n] = *reinterpret_cast<const bf16x8*>(&w2t[(size_t)(nb2 + n*16 + (lane & 15)) * 128 + ko]);
      #pragma unroll
      for (int m = 0; m < 2; ++m)
        #pragma unroll
        for (int n = 0; n < 4; ++n)
          acc2[m][n] = __builtin_amdgcn_mfma_f32_16x16x32_bf16(af[m], bfr[n], acc2[m][n], 0, 0, 0);
    }
    #pragma unroll
    for (int n = 0; n < 4; ++n) {
      float bb = b2[nb2 + n*16 + (lane & 15)];
      #pragma unroll
      for (int m = 0; m < 2; ++m) {
        int r0 = mb + m*16 + ((lane >> 4) << 2);
        int c  = nb2 + n*16 + (lane & 15);
        #pragma unroll
        for (int r = 0; r < 4; ++r) {
          int row = row0 + r0 + r;
          if (row < N) {
            float o = bf2f(A1[r0 + r][32 + c]) + silu_f(acc2[m][n][r] + bb);
            __builtin_nontemporal_store(o, &node_out[(size_t)row * 128 + c]);
          }
        }
      }
    }
  } else {
    // ---------------- edge path ----------------
    const int eb = bid - (bid + 1) / 5;
    if (eb >= nEdgeBlk) return;
    const int e0 = eb * EBK;
    const unsigned short* wet = wsw;
    auto& A = sm.e.A;

    // e_u -> A cols 0..63 (float4/lane; wave reads 1KB contiguous)
    #pragma unroll
    for (int p = 0; p < 8; ++p) {
      int i = p * 256 + t;
      int row = i >> 4, cq = i & 15;
      if (e0 + row < Eu) {
        const fvec4 v = __builtin_nontemporal_load(
            reinterpret_cast<const fvec4*>(&e_t[(size_t)(e0 + row) * 64 + cq * 4]));
        uint2 pk;
        pk.x = f2bf(v.x) | ((unsigned)f2bf(v.y) << 16);
        pk.y = f2bf(v.z) | ((unsigned)f2bf(v.w) << 16);
        *reinterpret_cast<uint2*>(&A[row][cq * 4]) = pk;
      }
    }
    // distances + d_input: 256 threads = 128 edges x 2; pairwise shfl swap
    {
      const int el = t >> 1, which = t & 1;
      const int e = e0 + el;
      float dcur = 0.0f;
      if (e < Eu) {
        int su = edge_src[e], du = edge_dst[e];
        const float* base = which ? dst_lig_x : x_t;
        float u0 = base[su*3+0] - base[du*3+0];
        float u1 = base[su*3+1] - base[du*3+1];
        float u2 = base[su*3+2] - base[du*3+2];
        dcur = sqrtf(fmaxf(u0*u0 + u1*u1 + u2*u2, 1e-8f));
      }
      float doth = __shfl_xor(dcur, 1);
      float dt_ = which ? doth : dcur;
      float d1_ = which ? dcur : doth;
      if (e < Eu) {
        #pragma unroll
        for (int q = 0; q < 8; ++q) {
          int m = which * 8 + q;
          float mu = 0.66666667f * (float)m;
          float a1 = (d1_ - mu) * 1.6f, a2 = (dt_ - mu) * 1.6f;
          A[el][69 + m] = f2bf(__expf(-a1*a1) - __expf(-a2*a2));
        }
      }
    }
    // dst_lig_e -> cols 64..68
    #pragma unroll
    for (int q = 0; q < 3; ++q) {
      int i = q * 256 + t;
      if (i < EBK * 5) {
        int el = i / 5, c = i - el * 5;
        if (e0 + el < Eu) A[el][64 + c] = f2bf(dst_lig_e[(size_t)(e0 + el) * 5 + c]);
      }
    }
    // zero cols 85..95
    #pragma unroll
    for (int q = 0; q < 6; ++q) {
      int i = q * 256 + t;
      if (i < EBK * 11) { int el = i / 11, c = i - el * 11; A[el][85 + c] = 0; }
    }
    __syncthreads();

    const int mb = w * 32;   // 2 m-tiles per wave, all 4 n-tiles

    f32x4 acc[2][4] = {};
    #pragma unroll 1
    for (int ks = 0; ks < 3; ++ks) {
      const int ko = ks * 32 + ((lane >> 4) << 3);
      bf16x8 af[2], bfr[4];
      #pragma unroll
      for (int m = 0; m < 2; ++m)
        af[m] = *reinterpret_cast<const bf16x8*>(&A[mb + m*16 + (lane & 15)][ko]);
      #pragma unroll
      for (int n = 0; n < 4; ++n)
        bfr[n] = *reinterpret_cast<const bf16x8*>(&wet[(size_t)(n*16 + (lane & 15)) * 96 + ko]);
      #pragma unroll
      for (int m = 0; m < 2; ++m)
        #pragma unroll
        for (int n = 0; n < 4; ++n)
          acc[m][n] = __builtin_amdgcn_mfma_f32_16x16x32_bf16(af[m], bfr[n], acc[m][n], 0, 0, 0);
    }
    #pragma unroll
    for (int n = 0; n < 4; ++n) {
      float bb = be[n*16 + (lane & 15)];
      #pragma unroll
      for (int m = 0; m < 2; ++m) {
        int r0 = mb + m*16 + ((lane >> 4) << 2);
        int c  = n*16 + (lane & 15);
        #pragma unroll
        for (int r = 0; r < 4; ++r) {
          size_t eidx = (size_t)e0 + r0 + r;
          if ((int)eidx < Eu) {
            float feat = bf2f(A[r0 + r][c]) + silu_f(acc[m][n][r] + bb);
            __builtin_nontemporal_store(feat, &e_out0[eidx * 64 + c]);
            __builtin_nontemporal_store(feat, &e_out1[eidx * 64 + c]);
          }
        }
      }
    }
  }
}

extern "C" void kernel_launch(void* const* d_in, const int* in_sizes, int n_in,
                              void* d_out, int out_size, void* d_ws, size_t ws_size,
                              hipStream_t stream) {
  const float* s_t       = (const float*)d_in[0];
  const float* x_t       = (const float*)d_in[1];
  const float* v_t       = (const float*)d_in[2];
  const float* e_t       = (const float*)d_in[3];
  const float* dst_lig_x = (const float*)d_in[4];
  const float* dst_lig_a = (const float*)d_in[5];
  const float* dst_lig_e = (const float*)d_in[6];
  const int*   edge_src  = (const int*)d_in[7];
  const int*   edge_dst  = (const int*)d_in[8];
  const float* W1        = (const float*)d_in[9];
  const float* b1        = (const float*)d_in[10];
  const float* W2        = (const float*)d_in[11];
  const float* b2        = (const float*)d_in[12];
  const float* We        = (const float*)d_in[13];
  const float* be        = (const float*)d_in[14];

  const int N  = in_sizes[0] / 128;       // 100000
  const int Eu = in_sizes[3] / 128;       // 800000

  float* out      = (float*)d_out;
  float* node_out = out;
  float* v_out    = out + (size_t)N * 128;
  float* e_out0   = v_out + (size_t)N * 12;
  float* e_out1   = e_out0 + (size_t)Eu * 64;

  unsigned short* wsp = (unsigned short*)d_ws;

  const int NBLK = (N + NBK - 1) / NBK;    // 1563
  const int EBLK = (Eu + EBK - 1) / EBK;   // 6250
  // node blocks at bid%5==4 -> 5*NBLK grid gives NBLK node slots, 4*NBLK edge slots
  int grid = 5 * NBLK;
  if (4 * NBLK < EBLK) grid = 5 * NBLK + (EBLK - 4 * NBLK) + ((EBLK - 4 * NBLK) / 4 + 1);

  prep_kernel<<<168, 256, 0, stream>>>(W1, W2, We, wsp);

  fused_kernel<<<grid, 256, 0, stream>>>(
      s_t, x_t, v_t, e_t, dst_lig_x, dst_lig_a, dst_lig_e, edge_src, edge_dst,
      wsp, b1, b2, be, node_out, v_out, e_out0, e_out1, N, Eu, NBLK, EBLK);
}

// Round 9
// 240.054 us; speedup vs baseline: 1.2163x; 1.2163x over previous
//
#include <hip/hip_runtime.h>
#include <math.h>

typedef short bf16x8 __attribute__((ext_vector_type(8)));
typedef float f32x4 __attribute__((ext_vector_type(4)));
typedef float fvec4 __attribute__((ext_vector_type(4)));   // for (nontemporal) vector loads

#define EBK 128   // edges per block (edge kernel)
#define NBK 64    // rows per block (node kernel)

__device__ __forceinline__ float silu_f(float x) {
  return x / (1.0f + __expf(-x));
}
__device__ __forceinline__ unsigned short f2bf(float x) {
  union { float f; unsigned u; } v; v.f = x;
  unsigned r = v.u + 0x7FFFu + ((v.u >> 16) & 1u);   // round-nearest-even
  return (unsigned short)(r >> 16);
}
__device__ __forceinline__ float bf2f(unsigned short h) {
  union { unsigned u; float f; } v; v.u = ((unsigned)h) << 16; return v.f;
}

// ---- prep: build bf16 transposed weights in ws ----
// wet:  [64 cols][96 K]   at ws[0..6144)        (K 85..95 zero)
// w1t:  [128 cols][160 K] at ws[6144..26624)
// w2t:  [128 cols][128 K] at ws[26624..43008)
__global__ __launch_bounds__(256)
void prep_kernel(const float* __restrict__ W1, const float* __restrict__ W2,
                 const float* __restrict__ We, unsigned short* __restrict__ ws)
{
  int i = blockIdx.x * 256 + threadIdx.x;
  if (i < 6144) {
    int col = i / 96, k = i - col * 96;
    float v = (k < 85) ? We[k * 64 + col] : 0.0f;
    ws[i] = f2bf(v);
  }
  int j = i - 6144;
  if (j >= 0 && j < 20480) {
    int col = j / 160, k = j - col * 160;
    ws[6144 + j] = f2bf(W1[k * 128 + col]);
  }
  int l = i - 26624;
  if (l >= 0 && l < 16384) {
    int col = l >> 7, k = l & 127;
    ws[26624 + l] = f2bf(W2[k * 128 + col]);
  }
}

// ---------------- node kernel: node_out + v_out (MFMA) ----------------
// 64 rows/block, 4 waves. A1[64][168] bf16 = [rbf16|a16|s128]+pad.
__global__ __launch_bounds__(256, 4)
void node_kernel(const float* __restrict__ s_t,
                 const float* __restrict__ x_t,
                 const float* __restrict__ v_t,
                 const float* __restrict__ dst_lig_x,
                 const float* __restrict__ dst_lig_a,
                 const unsigned short* __restrict__ w1t, const float* __restrict__ b1,
                 const unsigned short* __restrict__ w2t, const float* __restrict__ b2,
                 float* __restrict__ node_out, float* __restrict__ v_out,
                 int N)
{
  __shared__ unsigned short A1[NBK][168];  // stride 84 words (%32=20) -> 2-way
  __shared__ unsigned short H [NBK][136];  // stride 68 words (%32=4)  -> 2-way
  const int t = threadIdx.x;
  const int row0 = blockIdx.x * NBK;
  const int w = t >> 6, lane = t & 63;

  // stage s_t -> A1 cols 32..159
  #pragma unroll
  for (int p = 0; p < 8; ++p) {
    int i = p * 256 + t;
    int row = i >> 5, q = i & 31;
    if (row0 + row < N) {
      const fvec4 v = __builtin_nontemporal_load(
          reinterpret_cast<const fvec4*>(&s_t[(size_t)(row0 + row) * 128 + q * 4]));
      uint2 pk;
      pk.x = f2bf(v.x) | ((unsigned)f2bf(v.y) << 16);
      pk.y = f2bf(v.z) | ((unsigned)f2bf(v.w) << 16);
      *reinterpret_cast<uint2*>(&A1[row][32 + q * 4]) = pk;
    }
  }
  // rbf + dst_lig_a -> A1 cols 0..31; v_out (broadcast distance recompute)
  #pragma unroll
  for (int p = 0; p < 4; ++p) {
    int i = p * 256 + t;
    int el = i >> 4, m = i & 15;
    int row = row0 + el;
    if (row < N) {
      float dx = dst_lig_x[row*3+0] - x_t[row*3+0];
      float dy = dst_lig_x[row*3+1] - x_t[row*3+1];
      float dz = dst_lig_x[row*3+2] - x_t[row*3+2];
      float dij = sqrtf(fmaxf(dx*dx + dy*dy + dz*dz, 1e-8f));
      float tt = (dij - 0.66666667f * (float)m) * 1.6f;
      A1[el][m]      = f2bf(__expf(-tt * tt));
      A1[el][16 + m] = f2bf(dst_lig_a[(size_t)row * 16 + m]);
      if (m < 12) {
        float val;
        if (m < 9)       val = v_t[(size_t)row * 12 + m];
        else if (m == 9) val = dx / dij;
        else if (m == 10)val = dy / dij;
        else             val = dz / dij;
        __builtin_nontemporal_store(val, &v_out[(size_t)row * 12 + m]);
      }
    }
  }
  __syncthreads();

  const int mb = (w & 1) * 32;   // 2 m-tiles
  const int nb = (w >> 1) * 64;  // 4 n-tiles

  // layer 1: K=160, 5 k-steps
  f32x4 acc[2][4] = {};
  #pragma unroll 1
  for (int ks = 0; ks < 5; ++ks) {
    const int ko = ks * 32 + ((lane >> 4) << 3);
    bf16x8 af[2], bfr[4];
    #pragma unroll
    for (int m = 0; m < 2; ++m)
      af[m] = *reinterpret_cast<const bf16x8*>(&A1[mb + m*16 + (lane & 15)][ko]);
    #pragma unroll
    for (int n = 0; n < 4; ++n)
      bfr[n] = *reinterpret_cast<const bf16x8*>(&w1t[(size_t)(nb + n*16 + (lane & 15)) * 160 + ko]);
    #pragma unroll
    for (int m = 0; m < 2; ++m)
      #pragma unroll
      for (int n = 0; n < 4; ++n)
        acc[m][n] = __builtin_amdgcn_mfma_f32_16x16x32_bf16(af[m], bfr[n], acc[m][n], 0, 0, 0);
  }
  #pragma unroll
  for (int n = 0; n < 4; ++n) {
    float bb = b1[nb + n*16 + (lane & 15)];
    #pragma unroll
    for (int m = 0; m < 2; ++m) {
      int r0 = mb + m*16 + ((lane >> 4) << 2);
      int c  = nb + n*16 + (lane & 15);
      #pragma unroll
      for (int r = 0; r < 4; ++r)
        H[r0 + r][c] = f2bf(silu_f(acc[m][n][r] + bb));
    }
  }
  __syncthreads();

  // layer 2: K=128, 4 k-steps
  f32x4 acc2[2][4] = {};
  #pragma unroll 1
  for (int ks = 0; ks < 4; ++ks) {
    const int ko = ks * 32 + ((lane >> 4) << 3);
    bf16x8 af[2], bfr[4];
    #pragma unroll
    for (int m = 0; m < 2; ++m)
      af[m] = *reinterpret_cast<const bf16x8*>(&H[mb + m*16 + (lane & 15)][ko]);
    #pragma unroll
    for (int n = 0; n < 4; ++n)
      bfr[n] = *reinterpret_cast<const bf16x8*>(&w2t[(size_t)(nb + n*16 + (lane & 15)) * 128 + ko]);
    #pragma unroll
    for (int m = 0; m < 2; ++m)
      #pragma unroll
      for (int n = 0; n < 4; ++n)
        acc2[m][n] = __builtin_amdgcn_mfma_f32_16x16x32_bf16(af[m], bfr[n], acc2[m][n], 0, 0, 0);
  }
  #pragma unroll
  for (int n = 0; n < 4; ++n) {
    float bb = b2[nb + n*16 + (lane & 15)];
    #pragma unroll
    for (int m = 0; m < 2; ++m) {
      int r0 = mb + m*16 + ((lane >> 4) << 2);
      int c  = nb + n*16 + (lane & 15);
      #pragma unroll
      for (int r = 0; r < 4; ++r) {
        int row = row0 + r0 + r;
        if (row < N) {
          float o = bf2f(A1[r0 + r][32 + c]) + silu_f(acc2[m][n][r] + bb);
          __builtin_nontemporal_store(o, &node_out[(size_t)row * 128 + c]);
        }
      }
    }
  }
}

// ---------------- edge kernel: e_out (MFMA, direct-global A-frags) ----------------
// 128 edges/block, 4 waves; wave w owns rows w*32..w*32+31.
// e_u A-fragments (k 0..63) load straight from global e_t (f32 -> bf16 in reg);
// only the 32-col tail [lig_e|dinp|zeros] lives in LDS (9 KB). Residual uses
// the original f32 e_t (L2-hot re-read).
__global__ __launch_bounds__(256, 6)
void edge_kernel(const float* __restrict__ e_t,
                 const float* __restrict__ x_t,
                 const float* __restrict__ dst_lig_x,
                 const float* __restrict__ dst_lig_e,
                 const int* __restrict__ edge_src,
                 const int* __restrict__ edge_dst,
                 const unsigned short* __restrict__ wet, const float* __restrict__ be,
                 float* __restrict__ e_out0, float* __restrict__ e_out1,
                 int Eu)
{
  __shared__ unsigned short T[EBK][36];   // cols 64..95 (pad 36: stride 18 words)
  const int t = threadIdx.x;
  const int e0 = blockIdx.x * EBK;
  const int w = t >> 6, lane = t & 63;

  // distances + d_input -> T cols 5..20 (global cols 69..84); pairwise shfl swap
  {
    const int el = t >> 1, which = t & 1;
    const int e = e0 + el;
    float dcur = 0.0f;
    if (e < Eu) {
      int su = edge_src[e], du = edge_dst[e];
      const float* base = which ? dst_lig_x : x_t;
      float u0 = base[su*3+0] - base[du*3+0];
      float u1 = base[su*3+1] - base[du*3+1];
      float u2 = base[su*3+2] - base[du*3+2];
      dcur = sqrtf(fmaxf(u0*u0 + u1*u1 + u2*u2, 1e-8f));
    }
    float doth = __shfl_xor(dcur, 1);
    float dt_ = which ? doth : dcur;
    float d1_ = which ? dcur : doth;
    if (e < Eu) {
      #pragma unroll
      for (int q = 0; q < 8; ++q) {
        int m = which * 8 + q;
        float mu = 0.66666667f * (float)m;
        float a1 = (d1_ - mu) * 1.6f, a2 = (dt_ - mu) * 1.6f;
        T[el][5 + m] = f2bf(__expf(-a1*a1) - __expf(-a2*a2));
      }
    }
  }
  // dst_lig_e -> T cols 0..4 (global 64..68)
  #pragma unroll
  for (int q = 0; q < 3; ++q) {
    int i = q * 256 + t;
    if (i < EBK * 5) {
      int el = i / 5, c = i - el * 5;
      if (e0 + el < Eu) T[el][c] = f2bf(dst_lig_e[(size_t)(e0 + el) * 5 + c]);
    }
  }
  // zeros -> T cols 21..31 (global 85..95)
  #pragma unroll
  for (int q = 0; q < 6; ++q) {
    int i = q * 256 + t;
    if (i < EBK * 11) { int el = i / 11, c = i - el * 11; T[el][21 + c] = 0; }
  }
  __syncthreads();

  const int mb = w * 32;             // 2 m-tiles per wave, all 4 n-tiles
  const int lr = lane & 15;
  const int koff = (lane >> 4) << 3; // k sub-offset within 32-wide k-step

  f32x4 acc[2][4] = {};
  // ks = 0,1: A-frag direct from global e_t (cols 0..63)
  #pragma unroll 1
  for (int ks = 0; ks < 2; ++ks) {
    bf16x8 af[2], bfr[4];
    #pragma unroll
    for (int m = 0; m < 2; ++m) {
      int row = e0 + mb + m*16 + lr;
      if (row >= Eu) row = Eu - 1;   // clamp (Eu%EBK==0 in practice)
      const float* ap = &e_t[(size_t)row * 64 + ks * 32 + koff];
      const fvec4 lo = *reinterpret_cast<const fvec4*>(ap);
      const fvec4 hi = *reinterpret_cast<const fvec4*>(ap + 4);
      union { bf16x8 v; unsigned u[4]; } pk;
      pk.u[0] = f2bf(lo.x) | ((unsigned)f2bf(lo.y) << 16);
      pk.u[1] = f2bf(lo.z) | ((unsigned)f2bf(lo.w) << 16);
      pk.u[2] = f2bf(hi.x) | ((unsigned)f2bf(hi.y) << 16);
      pk.u[3] = f2bf(hi.z) | ((unsigned)f2bf(hi.w) << 16);
      af[m] = pk.v;
    }
    #pragma unroll
    for (int n = 0; n < 4; ++n)
      bfr[n] = *reinterpret_cast<const bf16x8*>(&wet[(size_t)(n*16 + lr) * 96 + ks * 32 + koff]);
    #pragma unroll
    for (int m = 0; m < 2; ++m)
      #pragma unroll
      for (int n = 0; n < 4; ++n)
        acc[m][n] = __builtin_amdgcn_mfma_f32_16x16x32_bf16(af[m], bfr[n], acc[m][n], 0, 0, 0);
  }
  // ks = 2: A-frag from LDS tail (cols 64..95)
  {
    bf16x8 af[2], bfr[4];
    #pragma unroll
    for (int m = 0; m < 2; ++m)
      af[m] = *reinterpret_cast<const bf16x8*>(&T[mb + m*16 + lr][koff]);
    #pragma unroll
    for (int n = 0; n < 4; ++n)
      bfr[n] = *reinterpret_cast<const bf16x8*>(&wet[(size_t)(n*16 + lr) * 96 + 64 + koff]);
    #pragma unroll
    for (int m = 0; m < 2; ++m)
      #pragma unroll
      for (int n = 0; n < 4; ++n)
        acc[m][n] = __builtin_amdgcn_mfma_f32_16x16x32_bf16(af[m], bfr[n], acc[m][n], 0, 0, 0);
  }

  // epilogue: residual from original f32 e_t (L2-hot)
  #pragma unroll
  for (int n = 0; n < 4; ++n) {
    float bb = be[n*16 + lr];
    #pragma unroll
    for (int m = 0; m < 2; ++m) {
      int r0 = mb + m*16 + ((lane >> 4) << 2);
      int c  = n*16 + lr;
      #pragma unroll
      for (int r = 0; r < 4; ++r) {
        size_t eidx = (size_t)e0 + r0 + r;
        if ((int)eidx < Eu) {
          float feat = e_t[eidx * 64 + c] + silu_f(acc[m][n][r] + bb);
          __builtin_nontemporal_store(feat, &e_out0[eidx * 64 + c]);
          __builtin_nontemporal_store(feat, &e_out1[eidx * 64 + c]);
        }
      }
    }
  }
}

extern "C" void kernel_launch(void* const* d_in, const int* in_sizes, int n_in,
                              void* d_out, int out_size, void* d_ws, size_t ws_size,
                              hipStream_t stream) {
  const float* s_t       = (const float*)d_in[0];
  const float* x_t       = (const float*)d_in[1];
  const float* v_t       = (const float*)d_in[2];
  const float* e_t       = (const float*)d_in[3];
  const float* dst_lig_x = (const float*)d_in[4];
  const float* dst_lig_a = (const float*)d_in[5];
  const float* dst_lig_e = (const float*)d_in[6];
  const int*   edge_src  = (const int*)d_in[7];
  const int*   edge_dst  = (const int*)d_in[8];
  const float* W1        = (const float*)d_in[9];
  const float* b1        = (const float*)d_in[10];
  const float* W2        = (const float*)d_in[11];
  const float* b2        = (const float*)d_in[12];
  const float* We        = (const float*)d_in[13];
  const float* be        = (const float*)d_in[14];

  const int N  = in_sizes[0] / 128;       // 100000
  const int Eu = in_sizes[3] / 128;       // 800000

  float* out      = (float*)d_out;
  float* node_out = out;
  float* v_out    = out + (size_t)N * 128;
  float* e_out0   = v_out + (size_t)N * 12;
  float* e_out1   = e_out0 + (size_t)Eu * 64;

  unsigned short* wsp = (unsigned short*)d_ws;
  unsigned short* wet = wsp;            // 6144
  unsigned short* w1t = wsp + 6144;     // 20480
  unsigned short* w2t = wsp + 26624;    // 16384

  prep_kernel<<<168, 256, 0, stream>>>(W1, W2, We, wsp);

  edge_kernel<<<(Eu + EBK - 1) / EBK, 256, 0, stream>>>(
      e_t, x_t, dst_lig_x, dst_lig_e, edge_src, edge_dst, wet, be,
      e_out0, e_out1, Eu);

  node_kernel<<<(N + NBK - 1) / NBK, 256, 0, stream>>>(
      s_t, x_t, v_t, dst_lig_x, dst_lig_a, w1t, b1, w2t, b2,
      node_out, v_out, N);
}